// Round 2
// baseline (499.492 us; speedup 1.0000x reference)
//
#include <hip/hip_runtime.h>
#include <hip/hip_bf16.h>
#include <math.h>

typedef __attribute__((ext_vector_type(4))) float f32x4;
typedef __attribute__((ext_vector_type(8))) short s16x8;
typedef __hip_bfloat16 bf16;

constexpr int TOK = 2048;   // B*S tokens
constexpr int DIM = 1024;   // hidden D
constexpr int HID = 512;    // expert inter H
constexpr int NE  = 16;     // experts
constexpr int NK  = 4;      // top-k
constexpr int NHS = 1024;   // shared inter HS
constexpr int NPAIR = TOK * NK;  // 8192 token-expert pairs

#define MFMA(a, b, c) __builtin_amdgcn_mfma_f32_16x16x32_bf16(a, b, c, 0, 0, 0)

#define GLOAD_LDS(gp, lp)                                                        \
  __builtin_amdgcn_global_load_lds(                                              \
      (const __attribute__((address_space(1))) unsigned int*)(gp),               \
      (__attribute__((address_space(3))) unsigned int*)(lp), 16, 0, 0)

// Stage a 128-row x 64-col bf16 tile from row-major src (leading dim ld) into
// LDS. LDS slot s of row r holds k-chunk s^(r&7) (XOR swizzle applied on the
// per-lane GLOBAL source; LDS dest stays linear as global_load_lds requires).
static __device__ __forceinline__ void stage_tile(const bf16* __restrict__ src, int ld,
                                                  int row0, int k0, bf16* lds, int tid) {
  int wid = tid >> 6;
#pragma unroll
  for (int i = 0; i < 4; ++i) {
    int c = i * 256 + tid;      // 16B-chunk index 0..1023
    int row = c >> 3;
    int slot = c & 7;
    int j = slot ^ (row & 7);
    const bf16* g = src + (size_t)(row0 + row) * ld + k0 + j * 8;
    bf16* l = lds + (size_t)(i * 256 + wid * 64) * 8;  // wave-uniform base
    GLOAD_LDS(g, l);
  }
}

// Gather variant: per-thread precomputed global row ids rows4[i].
static __device__ __forceinline__ void stage_gather(const bf16* __restrict__ src, int ld,
                                                    const int* rows4, int k0, bf16* lds,
                                                    int tid) {
  int wid = tid >> 6;
#pragma unroll
  for (int i = 0; i < 4; ++i) {
    int c = i * 256 + tid;
    int row = c >> 3;
    int slot = c & 7;
    int j = slot ^ (row & 7);
    const bf16* g = src + (size_t)rows4[i] * ld + k0 + j * 8;
    bf16* l = lds + (size_t)(i * 256 + wid * 64) * 8;
    GLOAD_LDS(g, l);
  }
}

static __device__ __forceinline__ s16x8 frag(const bf16* lds, int row, int kc) {
  return *(const s16x8*)(lds + row * 64 + ((kc ^ (row & 7)) << 3));
}

// ---------------- cast / transpose ----------------

struct bf16x4 { bf16 a, b, c, d; };

__global__ void cast_x_kernel(const float* __restrict__ x, bf16* __restrict__ xb, int n) {
  int idx = (blockIdx.x * blockDim.x + threadIdx.x) * 4;
  if (idx < n) {
    float4 v = *(const float4*)(x + idx);
    bf16x4 o{__float2bfloat16(v.x), __float2bfloat16(v.y),
             __float2bfloat16(v.z), __float2bfloat16(v.w)};
    *reinterpret_cast<bf16x4*>(xb + idx) = o;
  }
}

// src: [batch][R][C] fp32 -> dst: [batch][C][R] bf16
__global__ void transpose_cast(const float* __restrict__ src, bf16* __restrict__ dst,
                               int R, int C) {
  __shared__ float t[32][33];
  size_t bo = (size_t)blockIdx.z * R * C;
  src += bo; dst += bo;
  int c0 = blockIdx.x * 32, r0 = blockIdx.y * 32;
  int tx = threadIdx.x, ty = threadIdx.y;  // 32 x 8
#pragma unroll
  for (int i = 0; i < 32; i += 8) t[ty + i][tx] = src[(size_t)(r0 + ty + i) * C + c0 + tx];
  __syncthreads();
#pragma unroll
  for (int i = 0; i < 32; i += 8)
    dst[(size_t)(c0 + ty + i) * R + r0 + tx] = __float2bfloat16(t[tx][ty + i]);
}

// ---------------- gating (fp32 exact) + top-k ----------------

__global__ __launch_bounds__(256) void gate_topk(const float* __restrict__ x,
                                                 const float* __restrict__ gw,
                                                 int* __restrict__ topi,
                                                 float* __restrict__ topw) {
  int t = blockIdx.x;
  int tid = threadIdx.x, lane = tid & 63, wid = tid >> 6;
  __shared__ float gv[NE];
  const float* xr = x + (size_t)t * DIM;
#pragma unroll
  for (int e4 = 0; e4 < 4; ++e4) {
    int e = wid * 4 + e4;
    const float* w = gw + (size_t)e * DIM;
    float s = 0.f;
    for (int i = lane; i < DIM; i += 64) s += xr[i] * w[i];
#pragma unroll
    for (int off = 32; off; off >>= 1) s += __shfl_xor(s, off);
    if (lane == 0) gv[e] = s;
  }
  __syncthreads();
  if (tid == 0) {
    float g[NE];
#pragma unroll
    for (int e = 0; e < NE; ++e) g[e] = 1.f / (1.f + expf(-gv[e]));
    bool used[NE] = {};
    int bi[NK]; float bv[NK];
    float sum = 0.f;
    for (int j = 0; j < NK; ++j) {      // lax.top_k tie-break: lowest index first
      int best = 0; float v = -1e30f;
      for (int e = 0; e < NE; ++e)
        if (!used[e] && g[e] > v) { v = g[e]; best = e; }
      used[best] = true; bi[j] = best; bv[j] = v; sum += v;
    }
    float inv = 1.f / sum;
#pragma unroll
    for (int j = 0; j < NK; ++j) {
      topi[t * NK + j] = bi[j];
      topw[t * NK + j] = bv[j] * inv;
    }
  }
}

// Deterministic per-expert compaction (token-major order). 1 block, 4 waves.
__global__ __launch_bounds__(256) void route_build(const int* __restrict__ topi,
                                                   const float* __restrict__ topw,
                                                   int* __restrict__ tok_list,
                                                   float* __restrict__ w_list,
                                                   int* __restrict__ counts,
                                                   int* __restrict__ offs) {
  __shared__ int cnt_s[NE], off_s[NE];
  int tid = threadIdx.x, lane = tid & 63, w = tid >> 6;
#pragma unroll
  for (int ei = 0; ei < 4; ++ei) {
    int e = w * 4 + ei;
    int cnt = 0;
    for (int base = 0; base < NPAIR; base += 64) {
      bool m = (topi[base + lane] == e);
      cnt += __popcll(__ballot(m));
    }
    if (lane == 0) cnt_s[e] = cnt;
  }
  __syncthreads();
  if (tid < NE) {
    int o = 0;
    for (int i = 0; i < tid; ++i) o += cnt_s[i];
    off_s[tid] = o; offs[tid] = o; counts[tid] = cnt_s[tid];
  }
  __syncthreads();
#pragma unroll
  for (int ei = 0; ei < 4; ++ei) {
    int e = w * 4 + ei;
    int run = off_s[e];
    for (int base = 0; base < NPAIR; base += 64) {
      int pair = base + lane;
      bool m = (topi[pair] == e);
      unsigned long long mask = __ballot(m);
      int rank = __popcll(mask & ((1ull << lane) - 1ull));
      if (m) {
        tok_list[run + rank] = pair >> 2;   // token id
        w_list[run + rank] = topw[pair];
      }
      run += __popcll(mask);
    }
  }
}

// ---------------- fused up-projection (shared expert) ----------------
// hs = bf16( silu(X @ Ws_in) * (X @ Vs_in) ),  M=2048 N=1024 K=1024

__global__ __launch_bounds__(256) void up_shared(const bf16* __restrict__ xb,
                                                 const bf16* __restrict__ w1t,
                                                 const bf16* __restrict__ w2t,
                                                 bf16* __restrict__ hs) {
  __shared__ alignas(16) bf16 As[128 * 64], B1s[128 * 64], B2s[128 * 64];
  int tid = threadIdx.x, lane = tid & 63, wid = tid >> 6;
  int wr = wid >> 1, wc = wid & 1;
  int m0 = blockIdx.x * 128, n0 = blockIdx.y * 128;
  f32x4 acc1[4][4], acc2[4][4];
  f32x4 z4 = {0.f, 0.f, 0.f, 0.f};
#pragma unroll
  for (int mi = 0; mi < 4; ++mi)
#pragma unroll
    for (int ni = 0; ni < 4; ++ni) { acc1[mi][ni] = z4; acc2[mi][ni] = z4; }

  for (int k0 = 0; k0 < DIM; k0 += 64) {
    __syncthreads();
    stage_tile(xb, DIM, m0, k0, As, tid);
    stage_tile(w1t, DIM, n0, k0, B1s, tid);
    stage_tile(w2t, DIM, n0, k0, B2s, tid);
    __syncthreads();
#pragma unroll
    for (int ks = 0; ks < 2; ++ks) {
      int r16 = lane & 15, kc = (ks << 2) + (lane >> 4);
      s16x8 a[4];
#pragma unroll
      for (int mi = 0; mi < 4; ++mi) a[mi] = frag(As, wr * 64 + mi * 16 + r16, kc);
#pragma unroll
      for (int ni = 0; ni < 4; ++ni) {
        s16x8 b1 = frag(B1s, wc * 64 + ni * 16 + r16, kc);
        s16x8 b2 = frag(B2s, wc * 64 + ni * 16 + r16, kc);
#pragma unroll
        for (int mi = 0; mi < 4; ++mi) {
          acc1[mi][ni] = MFMA(a[mi], b1, acc1[mi][ni]);
          acc2[mi][ni] = MFMA(a[mi], b2, acc2[mi][ni]);
        }
      }
    }
  }
  int r0 = m0 + wr * 64, c0 = n0 + wc * 64;
#pragma unroll
  for (int mi = 0; mi < 4; ++mi)
#pragma unroll
    for (int ni = 0; ni < 4; ++ni)
#pragma unroll
      for (int i = 0; i < 4; ++i) {
        int r = r0 + mi * 16 + (lane >> 4) * 4 + i;
        int c = c0 + ni * 16 + (lane & 15);
        float z = acc1[mi][ni][i], v = acc2[mi][ni][i];
        float h = z / (1.f + __expf(-z)) * v;
        hs[(size_t)r * NHS + c] = __float2bfloat16(h);
      }
}

// ---------------- sparse routed up-projection ----------------
// For expert e's cnt tokens: hre[pair] = bf16(silu(x@Win)*(x@Vin)*w_pair), N=512

__global__ __launch_bounds__(256) void up_routed(const bf16* __restrict__ xb,
                                                 const bf16* __restrict__ w1t_all,
                                                 const bf16* __restrict__ w2t_all,
                                                 const int* __restrict__ tok_list,
                                                 const float* __restrict__ w_list,
                                                 const int* __restrict__ counts,
                                                 const int* __restrict__ offs,
                                                 bf16* __restrict__ hre) {
  int e = blockIdx.z;
  int cnt = counts[e];
  int m0 = blockIdx.x * 128;
  if (m0 >= cnt) return;
  int off_e = offs[e];
  const bf16* w1t = w1t_all + (size_t)e * HID * DIM;
  const bf16* w2t = w2t_all + (size_t)e * HID * DIM;
  int tid = threadIdx.x, lane = tid & 63, wid = tid >> 6;
  int wr = wid >> 1, wc = wid & 1;
  int n0 = blockIdx.y * 128;

  int rows4[4];
#pragma unroll
  for (int i = 0; i < 4; ++i) {
    int r = (i * 256 + tid) >> 3;                 // local row 0..127
    rows4[i] = tok_list[off_e + min(m0 + r, cnt - 1)];
  }

  __shared__ alignas(16) bf16 As[128 * 64], B1s[128 * 64], B2s[128 * 64];
  f32x4 acc1[4][4], acc2[4][4];
  f32x4 z4 = {0.f, 0.f, 0.f, 0.f};
#pragma unroll
  for (int mi = 0; mi < 4; ++mi)
#pragma unroll
    for (int ni = 0; ni < 4; ++ni) { acc1[mi][ni] = z4; acc2[mi][ni] = z4; }

  for (int k0 = 0; k0 < DIM; k0 += 64) {
    __syncthreads();
    stage_gather(xb, DIM, rows4, k0, As, tid);
    stage_tile(w1t, DIM, n0, k0, B1s, tid);
    stage_tile(w2t, DIM, n0, k0, B2s, tid);
    __syncthreads();
#pragma unroll
    for (int ks = 0; ks < 2; ++ks) {
      int r16 = lane & 15, kc = (ks << 2) + (lane >> 4);
      s16x8 a[4];
#pragma unroll
      for (int mi = 0; mi < 4; ++mi) a[mi] = frag(As, wr * 64 + mi * 16 + r16, kc);
#pragma unroll
      for (int ni = 0; ni < 4; ++ni) {
        s16x8 b1 = frag(B1s, wc * 64 + ni * 16 + r16, kc);
        s16x8 b2 = frag(B2s, wc * 64 + ni * 16 + r16, kc);
#pragma unroll
        for (int mi = 0; mi < 4; ++mi) {
          acc1[mi][ni] = MFMA(a[mi], b1, acc1[mi][ni]);
          acc2[mi][ni] = MFMA(a[mi], b2, acc2[mi][ni]);
        }
      }
    }
  }
  int c0 = n0 + wc * 64;
#pragma unroll
  for (int mi = 0; mi < 4; ++mi)
#pragma unroll
    for (int ni = 0; ni < 4; ++ni)
#pragma unroll
      for (int i = 0; i < 4; ++i) {
        int r = wr * 64 + mi * 16 + (lane >> 4) * 4 + i;  // local row
        int gr = m0 + r;
        if (gr < cnt) {
          int c = c0 + ni * 16 + (lane & 15);
          float z = acc1[mi][ni][i], v = acc2[mi][ni][i];
          float h = z / (1.f + __expf(-z)) * v * w_list[off_e + gr];
          hre[(size_t)(off_e + gr) * HID + c] = __float2bfloat16(h);
        }
      }
}

// ---------------- shared down-projection (plain write) ----------------
// out = hs @ Ws_out,  M=2048 N=1024 K=1024

__global__ __launch_bounds__(256) void down_shared(const bf16* __restrict__ hs,
                                                   const bf16* __restrict__ wsoutT,
                                                   float* __restrict__ out) {
  __shared__ alignas(16) bf16 As[128 * 64], Bs[128 * 64];
  int tid = threadIdx.x, lane = tid & 63, wid = tid >> 6;
  int wr = wid >> 1, wc = wid & 1;
  int m0 = blockIdx.x * 128, n0 = blockIdx.y * 128;
  f32x4 acc[4][4];
  f32x4 z4 = {0.f, 0.f, 0.f, 0.f};
#pragma unroll
  for (int mi = 0; mi < 4; ++mi)
#pragma unroll
    for (int ni = 0; ni < 4; ++ni) acc[mi][ni] = z4;

  for (int k0 = 0; k0 < NHS; k0 += 64) {
    __syncthreads();
    stage_tile(hs, NHS, m0, k0, As, tid);
    stage_tile(wsoutT, NHS, n0, k0, Bs, tid);
    __syncthreads();
#pragma unroll
    for (int ks = 0; ks < 2; ++ks) {
      int r16 = lane & 15, kc = (ks << 2) + (lane >> 4);
      s16x8 a[4];
#pragma unroll
      for (int mi = 0; mi < 4; ++mi) a[mi] = frag(As, wr * 64 + mi * 16 + r16, kc);
#pragma unroll
      for (int ni = 0; ni < 4; ++ni) {
        s16x8 b = frag(Bs, wc * 64 + ni * 16 + r16, kc);
#pragma unroll
        for (int mi = 0; mi < 4; ++mi) acc[mi][ni] = MFMA(a[mi], b, acc[mi][ni]);
      }
    }
  }
  int r0 = m0 + wr * 64, c0 = n0 + wc * 64;
#pragma unroll
  for (int mi = 0; mi < 4; ++mi)
#pragma unroll
    for (int ni = 0; ni < 4; ++ni)
#pragma unroll
      for (int i = 0; i < 4; ++i) {
        int r = r0 + mi * 16 + (lane >> 4) * 4 + i;
        int c = c0 + ni * 16 + (lane & 15);
        out[(size_t)r * DIM + c] = acc[mi][ni][i];
      }
}

// ---------------- sparse routed down-projection (atomic scatter) ----------

__global__ __launch_bounds__(256) void down_routed(const bf16* __restrict__ hre,
                                                   const bf16* __restrict__ ewoutT,
                                                   const int* __restrict__ tok_list,
                                                   const int* __restrict__ counts,
                                                   const int* __restrict__ offs,
                                                   float* __restrict__ out) {
  int e = blockIdx.z;
  int cnt = counts[e];
  int m0 = blockIdx.x * 128;
  if (m0 >= cnt) return;
  int off_e = offs[e];
  const bf16* A = hre + (size_t)off_e * HID;  // rows padded at buffer end
  const bf16* B = ewoutT + (size_t)e * DIM * HID;
  int tid = threadIdx.x, lane = tid & 63, wid = tid >> 6;
  int wr = wid >> 1, wc = wid & 1;
  int n0 = blockIdx.y * 128;

  __shared__ alignas(16) bf16 As[128 * 64], Bs[128 * 64];
  f32x4 acc[4][4];
  f32x4 z4 = {0.f, 0.f, 0.f, 0.f};
#pragma unroll
  for (int mi = 0; mi < 4; ++mi)
#pragma unroll
    for (int ni = 0; ni < 4; ++ni) acc[mi][ni] = z4;

  for (int k0 = 0; k0 < HID; k0 += 64) {
    __syncthreads();
    stage_tile(A, HID, m0, k0, As, tid);
    stage_tile(B, HID, n0, k0, Bs, tid);
    __syncthreads();
#pragma unroll
    for (int ks = 0; ks < 2; ++ks) {
      int r16 = lane & 15, kc = (ks << 2) + (lane >> 4);
      s16x8 a[4];
#pragma unroll
      for (int mi = 0; mi < 4; ++mi) a[mi] = frag(As, wr * 64 + mi * 16 + r16, kc);
#pragma unroll
      for (int ni = 0; ni < 4; ++ni) {
        s16x8 b = frag(Bs, wc * 64 + ni * 16 + r16, kc);
#pragma unroll
        for (int mi = 0; mi < 4; ++mi) acc[mi][ni] = MFMA(a[mi], b, acc[mi][ni]);
      }
    }
  }
  int c0 = n0 + wc * 64;
#pragma unroll
  for (int mi = 0; mi < 4; ++mi)
#pragma unroll
    for (int ni = 0; ni < 4; ++ni)
#pragma unroll
      for (int i = 0; i < 4; ++i) {
        int r = wr * 64 + mi * 16 + (lane >> 4) * 4 + i;
        int gr = m0 + r;
        if (gr < cnt) {
          int tok = tok_list[off_e + gr];
          int c = c0 + ni * 16 + (lane & 15);
          atomicAdd(&out[(size_t)tok * DIM + c], acc[mi][ni][i]);
        }
      }
}

// ---------------- launcher ----------------

extern "C" void kernel_launch(void* const* d_in, const int* in_sizes, int n_in,
                              void* d_out, int out_size, void* d_ws, size_t ws_size,
                              hipStream_t stream) {
  const float* x      = (const float*)d_in[0];
  const float* gw     = (const float*)d_in[1];
  const float* ws_in  = (const float*)d_in[2];
  const float* vs_in  = (const float*)d_in[3];
  const float* ws_out = (const float*)d_in[4];
  const float* e_win  = (const float*)d_in[5];
  const float* e_vin  = (const float*)d_in[6];
  const float* e_wout = (const float*)d_in[7];
  float* out = (float*)d_out;

  // Workspace layout, peak ~52.4 MB (regions reused across phases).
  char* p = (char*)d_ws;
  bf16* xb     = (bf16*)p;  p += (size_t)TOK * DIM * 2;          // 4 MB
  bf16* wsinT  = (bf16*)p;                                       // 2 MB
  bf16* wsoutT = wsinT;                                          // reused after up_shared
  p += (size_t)NHS * DIM * 2;
  bf16* vsinT  = (bf16*)p;  p += (size_t)NHS * DIM * 2;          // 2 MB
  bf16* hsb    = (bf16*)p;  p += (size_t)TOK * NHS * 2;          // 4 MB
  bf16* ewinT  = (bf16*)p;                                       // 16 MB
  bf16* ewoutT = ewinT;                                          // reused after up_routed
  p += (size_t)NE * DIM * HID * 2;
  bf16* evinT  = (bf16*)p;  p += (size_t)NE * DIM * HID * 2;     // 16 MB
  bf16* hre    = (bf16*)p;  p += (size_t)(NPAIR + 128) * HID * 2; // 8.25 MB (+pad rows)
  int*   topi     = (int*)p;    p += (size_t)NPAIR * 4;
  float* topw     = (float*)p;  p += (size_t)NPAIR * 4;
  int*   tok_list = (int*)p;    p += (size_t)NPAIR * 4;
  float* w_list   = (float*)p;  p += (size_t)NPAIR * 4;
  int*   counts   = (int*)p;    p += 64;
  int*   offs     = (int*)p;    p += 64;

  cast_x_kernel<<<(TOK * DIM / 4 + 255) / 256, 256, 0, stream>>>(x, xb, TOK * DIM);
  transpose_cast<<<dim3(32, 32, 1),  dim3(32, 8), 0, stream>>>(ws_in, wsinT, DIM, NHS);
  transpose_cast<<<dim3(32, 32, 1),  dim3(32, 8), 0, stream>>>(vs_in, vsinT, DIM, NHS);
  transpose_cast<<<dim3(16, 32, 16), dim3(32, 8), 0, stream>>>(e_win, ewinT, DIM, HID);
  transpose_cast<<<dim3(16, 32, 16), dim3(32, 8), 0, stream>>>(e_vin, evinT, DIM, HID);

  gate_topk<<<TOK, 256, 0, stream>>>(x, gw, topi, topw);
  route_build<<<1, 256, 0, stream>>>(topi, topw, tok_list, w_list, counts, offs);

  up_shared<<<dim3(16, 8), 256, 0, stream>>>(xb, wsinT, vsinT, hsb);
  up_routed<<<dim3(16, 4, NE), 256, 0, stream>>>(xb, ewinT, evinT, tok_list, w_list,
                                                 counts, offs, hre);

  // Reuse regions: safe because stream-ordered after the up kernels.
  transpose_cast<<<dim3(32, 32, 1),  dim3(32, 8), 0, stream>>>(ws_out, wsoutT, NHS, DIM);
  transpose_cast<<<dim3(32, 16, 16), dim3(32, 8), 0, stream>>>(e_wout, ewoutT, HID, DIM);

  down_shared<<<dim3(16, 8), 256, 0, stream>>>(hsb, wsoutT, out);
  down_routed<<<dim3(16, 8, NE), 256, 0, stream>>>(hre, ewoutT, tok_list, counts, offs, out);
}

// Round 3
// 314.399 us; speedup vs baseline: 1.5887x; 1.5887x over previous
//
#include <hip/hip_runtime.h>
#include <hip/hip_bf16.h>
#include <math.h>

typedef __attribute__((ext_vector_type(4))) float f32x4;
typedef __attribute__((ext_vector_type(8))) short s16x8;
typedef __hip_bfloat16 bf16;

constexpr int TOK = 2048;   // B*S tokens
constexpr int DIM = 1024;   // hidden D
constexpr int HID = 512;    // expert inter H
constexpr int NE  = 16;     // experts
constexpr int NK  = 4;      // top-k
constexpr int NHS = 1024;   // shared inter HS
constexpr int NPAIR = TOK * NK;  // 8192 token-expert pairs

#define MFMA(a, b, c) __builtin_amdgcn_mfma_f32_16x16x32_bf16(a, b, c, 0, 0, 0)

#define GLOAD_LDS(gp, lp)                                                        \
  __builtin_amdgcn_global_load_lds(                                              \
      (const __attribute__((address_space(1))) unsigned int*)(gp),               \
      (__attribute__((address_space(3))) unsigned int*)(lp), 16, 0, 0)

// Stage a (CH*32)-row x 64-col bf16 tile into LDS. rows[i] gives the global
// row for this thread's i-th 16B chunk. LDS slot s of row r holds k-chunk
// s^(r&7): XOR swizzle applied on the per-lane GLOBAL source address; the LDS
// destination stays linear (global_load_lds requirement). 0 bank conflicts
// measured in round 2.
template <int CH>
static __device__ __forceinline__ void stage_rows(const bf16* __restrict__ src, int ld,
                                                  const int* rows, int k0, bf16* lds,
                                                  int tid) {
  int wid = tid >> 6;
#pragma unroll
  for (int i = 0; i < CH; ++i) {
    int c = i * 256 + tid;      // 16B-chunk index
    int row = c >> 3;
    int slot = c & 7;
    int j = slot ^ (row & 7);
    const bf16* g = src + (size_t)rows[i] * ld + k0 + j * 8;
    bf16* l = lds + (size_t)(i * 256 + wid * 64) * 8;  // wave-uniform base
    GLOAD_LDS(g, l);
  }
}

static __device__ __forceinline__ s16x8 frag(const bf16* lds, int row, int kc) {
  return *(const s16x8*)(lds + row * 64 + ((kc ^ (row & 7)) << 3));
}

struct bf16x4 { bf16 a, b, c, d; };

// ---------------- fused transpose+cast prep kernels ----------------
// src [R][C] fp32 -> dst [C][R] bf16, 32x32 tiles, 256 threads flat.

static __device__ __forceinline__ void tr_tile(const float* __restrict__ src,
                                               bf16* __restrict__ dst, int R, int C,
                                               int bx, int by, float t[32][33], int tid) {
  int tx = tid & 31, ty = tid >> 5;  // 32 x 8
  int c0 = bx * 32, r0 = by * 32;
#pragma unroll
  for (int i = 0; i < 32; i += 8) t[ty + i][tx] = src[(size_t)(r0 + ty + i) * C + c0 + tx];
  __syncthreads();
#pragma unroll
  for (int i = 0; i < 32; i += 8)
    dst[(size_t)(c0 + ty + i) * R + r0 + tx] = __float2bfloat16(t[tx][ty + i]);
}

__global__ __launch_bounds__(256) void prep1(const float* __restrict__ ws_in,
                                             const float* __restrict__ vs_in,
                                             const float* __restrict__ e_win,
                                             const float* __restrict__ e_vin,
                                             bf16* __restrict__ wsinT, bf16* __restrict__ vsinT,
                                             bf16* __restrict__ ewinT, bf16* __restrict__ evinT) {
  __shared__ float t[32][33];
  int bid = blockIdx.x, tid = threadIdx.x;
  if (bid < 1024) {
    tr_tile(ws_in, wsinT, DIM, NHS, bid & 31, bid >> 5, t, tid);
  } else if (bid < 2048) {
    int b = bid - 1024;
    tr_tile(vs_in, vsinT, DIM, NHS, b & 31, b >> 5, t, tid);
  } else if (bid < 10240) {
    int b = bid - 2048, e = b >> 9; b &= 511;
    tr_tile(e_win + (size_t)e * DIM * HID, ewinT + (size_t)e * DIM * HID,
            DIM, HID, b & 15, b >> 4, t, tid);
  } else {
    int b = bid - 10240, e = b >> 9; b &= 511;
    tr_tile(e_vin + (size_t)e * DIM * HID, evinT + (size_t)e * DIM * HID,
            DIM, HID, b & 15, b >> 4, t, tid);
  }
}

__global__ __launch_bounds__(256) void prep2(const float* __restrict__ ws_out,
                                             const float* __restrict__ e_wout,
                                             bf16* __restrict__ wsoutT,
                                             bf16* __restrict__ ewoutT) {
  __shared__ float t[32][33];
  int bid = blockIdx.x, tid = threadIdx.x;
  if (bid < 1024) {
    tr_tile(ws_out, wsoutT, NHS, DIM, bid & 31, bid >> 5, t, tid);
  } else {
    int b = bid - 1024, e = b >> 9; b &= 511;
    tr_tile(e_wout + (size_t)e * HID * DIM, ewoutT + (size_t)e * HID * DIM,
            HID, DIM, b & 31, b >> 5, t, tid);
  }
}

// ---------------- gating (fp32 exact) + x cast ----------------

__global__ __launch_bounds__(256) void gate_cast(const float* __restrict__ x,
                                                 const float* __restrict__ gw,
                                                 bf16* __restrict__ xb,
                                                 int* __restrict__ topi,
                                                 float* __restrict__ topw) {
  int t = blockIdx.x;
  int tid = threadIdx.x, lane = tid & 63, wid = tid >> 6;
  const float* xr = x + (size_t)t * DIM;
  {  // cast this token's row to bf16
    float4 v = *(const float4*)(xr + tid * 4);
    bf16x4 o{__float2bfloat16(v.x), __float2bfloat16(v.y),
             __float2bfloat16(v.z), __float2bfloat16(v.w)};
    *reinterpret_cast<bf16x4*>(xb + (size_t)t * DIM + tid * 4) = o;
  }
  __shared__ float gv[NE];
#pragma unroll
  for (int e4 = 0; e4 < 4; ++e4) {
    int e = wid * 4 + e4;
    const float* w = gw + (size_t)e * DIM;
    float s = 0.f;
    for (int i = lane; i < DIM; i += 64) s += xr[i] * w[i];
#pragma unroll
    for (int off = 32; off; off >>= 1) s += __shfl_xor(s, off);
    if (lane == 0) gv[e] = s;
  }
  __syncthreads();
  if (tid == 0) {
    float g[NE];
#pragma unroll
    for (int e = 0; e < NE; ++e) g[e] = 1.f / (1.f + expf(-gv[e]));
    bool used[NE] = {};
    int bi[NK]; float bv[NK];
    float sum = 0.f;
    for (int j = 0; j < NK; ++j) {      // lax.top_k tie-break: lowest index first
      int best = 0; float v = -1e30f;
      for (int e = 0; e < NE; ++e)
        if (!used[e] && g[e] > v) { v = g[e]; best = e; }
      used[best] = true; bi[j] = best; bv[j] = v; sum += v;
    }
    float inv = 1.f / sum;
#pragma unroll
    for (int j = 0; j < NK; ++j) {
      topi[t * NK + j] = bi[j];
      topw[t * NK + j] = bv[j] * inv;
    }
  }
}

// Deterministic per-expert compaction (token-major order) + job-segment lists.
__global__ __launch_bounds__(256) void route_build(const int* __restrict__ topi,
                                                   const float* __restrict__ topw,
                                                   int* __restrict__ tok_list,
                                                   float* __restrict__ w_list,
                                                   int* __restrict__ counts,
                                                   int* __restrict__ offs,
                                                   int* __restrict__ seg_up,
                                                   int* __restrict__ nseg_up,
                                                   int* __restrict__ seg_dn,
                                                   int* __restrict__ nseg_dn) {
  __shared__ int cnt_s[NE], off_s[NE];
  int tid = threadIdx.x, lane = tid & 63, w = tid >> 6;
#pragma unroll
  for (int ei = 0; ei < 4; ++ei) {
    int e = w * 4 + ei;
    int cnt = 0;
    for (int base = 0; base < NPAIR; base += 64) {
      bool m = (topi[base + lane] == e);
      cnt += __popcll(__ballot(m));
    }
    if (lane == 0) cnt_s[e] = cnt;
  }
  __syncthreads();
  if (tid < NE) {
    int o = 0;
    for (int i = 0; i < tid; ++i) o += cnt_s[i];
    off_s[tid] = o; offs[tid] = o; counts[tid] = cnt_s[tid];
  }
  __syncthreads();
  if (tid == 0) {  // build (expert, m0) segment lists for the GEMM job grids
    int s = 0;
    for (int e = 0; e < NE; ++e)
      for (int m = 0; m < cnt_s[e]; m += 64) seg_up[s++] = (e << 16) | m;
    nseg_up[0] = s;
    s = 0;
    for (int e = 0; e < NE; ++e)
      for (int m = 0; m < cnt_s[e]; m += 128) seg_dn[s++] = (e << 16) | m;
    nseg_dn[0] = s;
  }
#pragma unroll
  for (int ei = 0; ei < 4; ++ei) {
    int e = w * 4 + ei;
    int run = off_s[e];
    for (int base = 0; base < NPAIR; base += 64) {
      int pair = base + lane;
      bool m = (topi[pair] == e);
      unsigned long long mask = __ballot(m);
      int rank = __popcll(mask & ((1ull << lane) - 1ull));
      if (m) {
        tok_list[run + rank] = pair >> 2;   // token id
        w_list[run + rank] = topw[pair];
      }
      run += __popcll(mask);
    }
  }
}

// ---------------- fused up-projection: shared + routed ----------------
// Job space: [0,256): shared 64x128 tiles (32m x 8n), K=1024.
//            [256, 256+4*nseg): routed: seg (e,m0) x 4 n-tiles, K=1024.
// Both have identical tile shape/cost -> good load balance.

__global__ __launch_bounds__(256) void up_all(
    const bf16* __restrict__ xb, const bf16* __restrict__ wsinT,
    const bf16* __restrict__ vsinT, const bf16* __restrict__ ewinT,
    const bf16* __restrict__ evinT, const int* __restrict__ tok_list,
    const float* __restrict__ w_list, const int* __restrict__ counts,
    const int* __restrict__ offs, const int* __restrict__ seg_up,
    const int* __restrict__ nseg_up, bf16* __restrict__ hsb,
    bf16* __restrict__ hre) {
  int j = blockIdx.x;
  int nj = 256 + 4 * nseg_up[0];
  if (j >= nj) return;
  int tid = threadIdx.x, lane = tid & 63, wid = tid >> 6;
  int wr = wid >> 1, wc = wid & 1;

  bool is_shared = (j < 256);
  int m0, n0, cnt = TOK, off_e = 0;
  const bf16 *B1, *B2;
  if (is_shared) {
    m0 = (j >> 3) * 64; n0 = (j & 7) * 128;
    B1 = wsinT + (size_t)n0 * DIM;
    B2 = vsinT + (size_t)n0 * DIM;
  } else {
    int r = j - 256, seg = r >> 2;
    n0 = (r & 3) * 128;
    int sv = seg_up[seg];
    int e = sv >> 16; m0 = sv & 0xffff;
    cnt = counts[e]; off_e = offs[e];
    B1 = ewinT + (size_t)e * HID * DIM + (size_t)n0 * DIM;
    B2 = evinT + (size_t)e * HID * DIM + (size_t)n0 * DIM;
  }

  int arows[2], brows[4];
#pragma unroll
  for (int i = 0; i < 2; ++i) {
    int row = (i * 256 + tid) >> 3;  // 0..63
    arows[i] = is_shared ? (m0 + row) : tok_list[off_e + min(m0 + row, cnt - 1)];
  }
#pragma unroll
  for (int i = 0; i < 4; ++i) brows[i] = (i * 256 + tid) >> 3;  // 0..127

  __shared__ alignas(16) bf16 As[64 * 64], B1s[128 * 64], B2s[128 * 64];
  f32x4 acc1[2][4], acc2[2][4];
  f32x4 z4 = {0.f, 0.f, 0.f, 0.f};
#pragma unroll
  for (int mi = 0; mi < 2; ++mi)
#pragma unroll
    for (int ni = 0; ni < 4; ++ni) { acc1[mi][ni] = z4; acc2[mi][ni] = z4; }

  for (int k0 = 0; k0 < DIM; k0 += 64) {
    __syncthreads();
    stage_rows<2>(xb, DIM, arows, k0, As, tid);
    stage_rows<4>(B1, DIM, brows, k0, B1s, tid);
    stage_rows<4>(B2, DIM, brows, k0, B2s, tid);
    __syncthreads();
#pragma unroll
    for (int ks = 0; ks < 2; ++ks) {
      int r16 = lane & 15, kc = (ks << 2) + (lane >> 4);
      s16x8 a0 = frag(As, wr * 32 + r16, kc);
      s16x8 a1 = frag(As, wr * 32 + 16 + r16, kc);
#pragma unroll
      for (int ni = 0; ni < 4; ++ni) {
        s16x8 b1 = frag(B1s, wc * 64 + ni * 16 + r16, kc);
        s16x8 b2 = frag(B2s, wc * 64 + ni * 16 + r16, kc);
        acc1[0][ni] = MFMA(a0, b1, acc1[0][ni]);
        acc1[1][ni] = MFMA(a1, b1, acc1[1][ni]);
        acc2[0][ni] = MFMA(a0, b2, acc2[0][ni]);
        acc2[1][ni] = MFMA(a1, b2, acc2[1][ni]);
      }
    }
  }
#pragma unroll
  for (int mi = 0; mi < 2; ++mi)
#pragma unroll
    for (int ni = 0; ni < 4; ++ni)
#pragma unroll
      for (int i = 0; i < 4; ++i) {
        int r = wr * 32 + mi * 16 + (lane >> 4) * 4 + i;
        int c = n0 + wc * 64 + ni * 16 + (lane & 15);
        float z = acc1[mi][ni][i], v = acc2[mi][ni][i];
        float h = z / (1.f + __expf(-z)) * v;
        if (is_shared) {
          hsb[(size_t)(m0 + r) * NHS + c] = __float2bfloat16(h);
        } else {
          int gr = m0 + r;
          if (gr < cnt)
            hre[(size_t)(off_e + gr) * HID + c] =
                __float2bfloat16(h * w_list[off_e + gr]);
        }
      }
}

// ---------------- fused down-projection: shared + routed (all-atomic) --------
// out zeroed by memset; every job atomicAdds its 128x128 fp32 tile.
// Job space: [0,128): shared 128x128 (16m x 8n), K=1024.
//            [128, 128+8*nseg): routed seg x 8 n-tiles, K=512.

__global__ __launch_bounds__(256) void down_all(
    const bf16* __restrict__ hsb, const bf16* __restrict__ wsoutT,
    const bf16* __restrict__ hre, const bf16* __restrict__ ewoutT,
    const int* __restrict__ tok_list, const int* __restrict__ counts,
    const int* __restrict__ offs, const int* __restrict__ seg_dn,
    const int* __restrict__ nseg_dn, float* __restrict__ out) {
  int j = blockIdx.x;
  int nj = 128 + 8 * nseg_dn[0];
  if (j >= nj) return;
  int tid = threadIdx.x, lane = tid & 63, wid = tid >> 6;
  int wr = wid >> 1, wc = wid & 1;

  bool is_shared = (j < 128);
  int m0, n0, cnt = TOK, off_e = 0, K, ld;
  const bf16 *A, *B;
  if (is_shared) {
    m0 = (j >> 3) * 128; n0 = (j & 7) * 128;
    A = hsb; ld = NHS; K = NHS;
    B = wsoutT + (size_t)n0 * NHS;
  } else {
    int r = j - 128, seg = r >> 3;
    n0 = (r & 7) * 128;
    int sv = seg_dn[seg];
    int e = sv >> 16; m0 = sv & 0xffff;
    cnt = counts[e]; off_e = offs[e];
    A = hre + (size_t)off_e * HID; ld = HID; K = HID;
    B = ewoutT + (size_t)e * DIM * HID + (size_t)n0 * HID;
  }

  int arows[4], brows[4];
#pragma unroll
  for (int i = 0; i < 4; ++i) {
    int row = (i * 256 + tid) >> 3;  // 0..127
    arows[i] = is_shared ? (m0 + row) : min(m0 + row, cnt - 1);
    brows[i] = row;
  }

  __shared__ alignas(16) bf16 As[128 * 64], Bs[128 * 64];
  f32x4 acc[4][4];
  f32x4 z4 = {0.f, 0.f, 0.f, 0.f};
#pragma unroll
  for (int mi = 0; mi < 4; ++mi)
#pragma unroll
    for (int ni = 0; ni < 4; ++ni) acc[mi][ni] = z4;

  for (int k0 = 0; k0 < K; k0 += 64) {
    __syncthreads();
    stage_rows<4>(A, ld, arows, k0, As, tid);
    stage_rows<4>(B, ld, brows, k0, Bs, tid);
    __syncthreads();
#pragma unroll
    for (int ks = 0; ks < 2; ++ks) {
      int r16 = lane & 15, kc = (ks << 2) + (lane >> 4);
      s16x8 a[4];
#pragma unroll
      for (int mi = 0; mi < 4; ++mi) a[mi] = frag(As, wr * 64 + mi * 16 + r16, kc);
#pragma unroll
      for (int ni = 0; ni < 4; ++ni) {
        s16x8 b = frag(Bs, wc * 64 + ni * 16 + r16, kc);
#pragma unroll
        for (int mi = 0; mi < 4; ++mi) acc[mi][ni] = MFMA(a[mi], b, acc[mi][ni]);
      }
    }
  }
#pragma unroll
  for (int mi = 0; mi < 4; ++mi)
#pragma unroll
    for (int ni = 0; ni < 4; ++ni)
#pragma unroll
      for (int i = 0; i < 4; ++i) {
        int r = wr * 64 + mi * 16 + (lane >> 4) * 4 + i;
        int c = n0 + wc * 64 + ni * 16 + (lane & 15);
        if (is_shared) {
          atomicAdd(&out[(size_t)(m0 + r) * DIM + c], acc[mi][ni][i]);
        } else {
          int gr = m0 + r;
          if (gr < cnt)
            atomicAdd(&out[(size_t)tok_list[off_e + gr] * DIM + c], acc[mi][ni][i]);
        }
      }
}

// ---------------- launcher ----------------

extern "C" void kernel_launch(void* const* d_in, const int* in_sizes, int n_in,
                              void* d_out, int out_size, void* d_ws, size_t ws_size,
                              hipStream_t stream) {
  const float* x      = (const float*)d_in[0];
  const float* gw     = (const float*)d_in[1];
  const float* ws_in  = (const float*)d_in[2];
  const float* vs_in  = (const float*)d_in[3];
  const float* ws_out = (const float*)d_in[4];
  const float* e_win  = (const float*)d_in[5];
  const float* e_vin  = (const float*)d_in[6];
  const float* e_wout = (const float*)d_in[7];
  float* out = (float*)d_out;

  // Workspace layout, peak ~52.5 MB (regions reused across phases; this size
  // passed validation in round 2 so ws_size >= ~52.5 MB).
  char* p = (char*)d_ws;
  bf16* xb     = (bf16*)p;  p += (size_t)TOK * DIM * 2;            // 4 MB
  bf16* wsinT  = (bf16*)p;                                         // 2 MB
  bf16* wsoutT = wsinT;                                            // reused after up_all
  p += (size_t)NHS * DIM * 2;
  bf16* vsinT  = (bf16*)p;  p += (size_t)NHS * DIM * 2;            // 2 MB
  bf16* hsb    = (bf16*)p;  p += (size_t)TOK * NHS * 2;            // 4 MB
  bf16* ewinT  = (bf16*)p;                                         // 16 MB
  bf16* ewoutT = ewinT;                                            // reused after up_all
  p += (size_t)NE * DIM * HID * 2;
  bf16* evinT  = (bf16*)p;  p += (size_t)NE * DIM * HID * 2;       // 16 MB
  bf16* hre    = (bf16*)p;  p += (size_t)(NPAIR + 128) * HID * 2;  // 8.25 MB
  int*   topi     = (int*)p;    p += (size_t)NPAIR * 4;
  float* topw     = (float*)p;  p += (size_t)NPAIR * 4;
  int*   tok_list = (int*)p;    p += (size_t)NPAIR * 4;
  float* w_list   = (float*)p;  p += (size_t)NPAIR * 4;
  int*   counts   = (int*)p;    p += 64;
  int*   offs     = (int*)p;    p += 64;
  int*   seg_up   = (int*)p;    p += 256 * 4;   // worst case 144 segs
  int*   nseg_up  = (int*)p;    p += 64;
  int*   seg_dn   = (int*)p;    p += 128 * 4;   // worst case 80 segs
  int*   nseg_dn  = (int*)p;    p += 64;

  prep1<<<18432, 256, 0, stream>>>(ws_in, vs_in, e_win, e_vin,
                                   wsinT, vsinT, ewinT, evinT);
  gate_cast<<<TOK, 256, 0, stream>>>(x, gw, xb, topi, topw);
  route_build<<<1, 256, 0, stream>>>(topi, topw, tok_list, w_list, counts, offs,
                                     seg_up, nseg_up, seg_dn, nseg_dn);

  up_all<<<1024, 256, 0, stream>>>(xb, wsinT, vsinT, ewinT, evinT, tok_list,
                                   w_list, counts, offs, seg_up, nseg_up, hsb, hre);

  // ws_out/e_wout transposes overwrite wsinT/ewinT (dead after up_all).
  prep2<<<9216, 256, 0, stream>>>(ws_out, e_wout, wsoutT, ewoutT);

  hipMemsetAsync(out, 0, (size_t)TOK * DIM * 4, stream);
  down_all<<<768, 256, 0, stream>>>(hsb, wsoutT, hre, ewoutT, tok_list, counts,
                                    offs, seg_dn, nseg_dn, out);
}

// Round 4
// 296.572 us; speedup vs baseline: 1.6842x; 1.0601x over previous
//
#include <hip/hip_runtime.h>
#include <hip/hip_bf16.h>
#include <math.h>

typedef __attribute__((ext_vector_type(4))) float f32x4;
typedef __attribute__((ext_vector_type(8))) short s16x8;
typedef __hip_bfloat16 bf16;

constexpr int TOK = 2048;   // B*S tokens
constexpr int DIM = 1024;   // hidden D
constexpr int HID = 512;    // expert inter H
constexpr int NE  = 16;     // experts
constexpr int NK  = 4;      // top-k
constexpr int NHS = 1024;   // shared inter HS
constexpr int NPAIR = TOK * NK;  // 8192 token-expert pairs

#define MFMA(a, b, c) __builtin_amdgcn_mfma_f32_16x16x32_bf16(a, b, c, 0, 0, 0)

#define GLOAD_LDS(gp, lp)                                                        \
  __builtin_amdgcn_global_load_lds(                                              \
      (const __attribute__((address_space(1))) unsigned int*)(gp),               \
      (__attribute__((address_space(3))) unsigned int*)(lp), 16, 0, 0)

// Stage a (CH*32)-row x 64-col bf16 tile into LDS. rows[i] gives the global
// row for this thread's i-th 16B chunk. LDS slot s of row r holds k-chunk
// s^(r&7): XOR swizzle applied on the per-lane GLOBAL source address; the LDS
// destination stays linear (global_load_lds requirement). 0 bank conflicts
// measured in round 2.
template <int CH>
static __device__ __forceinline__ void stage_rows(const bf16* __restrict__ src, int ld,
                                                  const int* rows, int k0, bf16* lds,
                                                  int tid) {
  int wid = tid >> 6;
#pragma unroll
  for (int i = 0; i < CH; ++i) {
    int c = i * 256 + tid;      // 16B-chunk index
    int row = c >> 3;
    int slot = c & 7;
    int j = slot ^ (row & 7);
    const bf16* g = src + (size_t)rows[i] * ld + k0 + j * 8;
    bf16* l = lds + (size_t)(i * 256 + wid * 64) * 8;  // wave-uniform base
    GLOAD_LDS(g, l);
  }
}

static __device__ __forceinline__ s16x8 frag(const bf16* lds, int row, int kc) {
  return *(const s16x8*)(lds + row * 64 + ((kc ^ (row & 7)) << 3));
}

struct bf16x4 { bf16 a, b, c, d; };

// ---------------- fused transpose+cast prep kernels ----------------
// src [R][C] fp32 -> dst [C][R] bf16, 32x32 tiles, 256 threads flat.

static __device__ __forceinline__ void tr_tile(const float* __restrict__ src,
                                               bf16* __restrict__ dst, int R, int C,
                                               int bx, int by, float t[32][33], int tid) {
  int tx = tid & 31, ty = tid >> 5;  // 32 x 8
  int c0 = bx * 32, r0 = by * 32;
#pragma unroll
  for (int i = 0; i < 32; i += 8) t[ty + i][tx] = src[(size_t)(r0 + ty + i) * C + c0 + tx];
  __syncthreads();
#pragma unroll
  for (int i = 0; i < 32; i += 8)
    dst[(size_t)(c0 + ty + i) * R + r0 + tx] = __float2bfloat16(t[tx][ty + i]);
}

__global__ __launch_bounds__(256) void prep1(const float* __restrict__ ws_in,
                                             const float* __restrict__ vs_in,
                                             const float* __restrict__ e_win,
                                             const float* __restrict__ e_vin,
                                             bf16* __restrict__ wsinT, bf16* __restrict__ vsinT,
                                             bf16* __restrict__ ewinT, bf16* __restrict__ evinT) {
  __shared__ float t[32][33];
  int bid = blockIdx.x, tid = threadIdx.x;
  if (bid < 1024) {
    tr_tile(ws_in, wsinT, DIM, NHS, bid & 31, bid >> 5, t, tid);
  } else if (bid < 2048) {
    int b = bid - 1024;
    tr_tile(vs_in, vsinT, DIM, NHS, b & 31, b >> 5, t, tid);
  } else if (bid < 10240) {
    int b = bid - 2048, e = b >> 9; b &= 511;
    tr_tile(e_win + (size_t)e * DIM * HID, ewinT + (size_t)e * DIM * HID,
            DIM, HID, b & 15, b >> 4, t, tid);
  } else {
    int b = bid - 10240, e = b >> 9; b &= 511;
    tr_tile(e_vin + (size_t)e * DIM * HID, evinT + (size_t)e * DIM * HID,
            DIM, HID, b & 15, b >> 4, t, tid);
  }
}

__global__ __launch_bounds__(256) void prep2(const float* __restrict__ ws_out,
                                             const float* __restrict__ e_wout,
                                             bf16* __restrict__ wsoutT,
                                             bf16* __restrict__ ewoutT) {
  __shared__ float t[32][33];
  int bid = blockIdx.x, tid = threadIdx.x;
  if (bid < 1024) {
    tr_tile(ws_out, wsoutT, NHS, DIM, bid & 31, bid >> 5, t, tid);
  } else {
    int b = bid - 1024, e = b >> 9; b &= 511;
    tr_tile(e_wout + (size_t)e * HID * DIM, ewoutT + (size_t)e * HID * DIM,
            HID, DIM, b & 31, b >> 5, t, tid);
  }
}

// ---------------- gating (fp32 exact) + x cast + expert histogram ----------

__global__ __launch_bounds__(256) void gate_cast(const float* __restrict__ x,
                                                 const float* __restrict__ gw,
                                                 bf16* __restrict__ xb,
                                                 int* __restrict__ topi,
                                                 float* __restrict__ topw,
                                                 int* __restrict__ counts) {
  int t = blockIdx.x;
  int tid = threadIdx.x, lane = tid & 63, wid = tid >> 6;
  const float* xr = x + (size_t)t * DIM;
  {  // cast this token's row to bf16
    float4 v = *(const float4*)(xr + tid * 4);
    bf16x4 o{__float2bfloat16(v.x), __float2bfloat16(v.y),
             __float2bfloat16(v.z), __float2bfloat16(v.w)};
    *reinterpret_cast<bf16x4*>(xb + (size_t)t * DIM + tid * 4) = o;
  }
  __shared__ float gv[NE];
#pragma unroll
  for (int e4 = 0; e4 < 4; ++e4) {
    int e = wid * 4 + e4;
    const float* w = gw + (size_t)e * DIM;
    float s = 0.f;
    for (int i = lane; i < DIM; i += 64) s += xr[i] * w[i];
#pragma unroll
    for (int off = 32; off; off >>= 1) s += __shfl_xor(s, off);
    if (lane == 0) gv[e] = s;
  }
  __syncthreads();
  if (tid == 0) {
    float g[NE];
#pragma unroll
    for (int e = 0; e < NE; ++e) g[e] = 1.f / (1.f + expf(-gv[e]));
    bool used[NE] = {};
    int bi[NK]; float bv[NK];
    float sum = 0.f;
    for (int j = 0; j < NK; ++j) {      // lax.top_k tie-break: lowest index first
      int best = 0; float v = -1e30f;
      for (int e = 0; e < NE; ++e)
        if (!used[e] && g[e] > v) { v = g[e]; best = e; }
      used[best] = true; bi[j] = best; bv[j] = v; sum += v;
    }
    float inv = 1.f / sum;
#pragma unroll
    for (int j = 0; j < NK; ++j) {
      topi[t * NK + j] = bi[j];
      topw[t * NK + j] = bv[j] * inv;
      atomicAdd(&counts[bi[j]], 1);
    }
  }
}

// Tiny serial kernel: offsets, segment lists, cursor reset. ~500 scalar ops.
__global__ __launch_bounds__(64) void route_small(const int* __restrict__ counts,
                                                  int* __restrict__ offs,
                                                  int* __restrict__ seg_up,
                                                  int* __restrict__ nseg_up,
                                                  int* __restrict__ seg_dn,
                                                  int* __restrict__ nseg_dn,
                                                  int* __restrict__ cursor) {
  if (threadIdx.x != 0) return;
  int o = 0;
  int offl[NE];
#pragma unroll
  for (int e = 0; e < NE; ++e) { offl[e] = o; offs[e] = o; cursor[e] = 0; o += counts[e]; }
  int s = 0;
  for (int e = 0; e < NE; ++e)
    for (int m = 0; m < counts[e]; m += 64) seg_up[s++] = (e << 16) | m;
  nseg_up[0] = s;
  s = 0;
  for (int e = 0; e < NE; ++e)
    for (int m = 0; m < counts[e]; m += 128) seg_dn[s++] = (e << 16) | m;
  nseg_dn[0] = s;
}

// Parallel compaction: each pair takes a slot via per-expert atomic cursor.
// Slot order within an expert is non-deterministic but output-invariant.
__global__ __launch_bounds__(256) void scatter_pairs(const int* __restrict__ topi,
                                                     const float* __restrict__ topw,
                                                     const int* __restrict__ offs,
                                                     int* __restrict__ cursor,
                                                     int* __restrict__ tok_list,
                                                     float* __restrict__ w_list) {
  int p = blockIdx.x * 256 + threadIdx.x;
  if (p >= NPAIR) return;
  int e = topi[p];
  int rank = atomicAdd(&cursor[e], 1);
  int slot = offs[e] + rank;
  tok_list[slot] = p >> 2;   // token id
  w_list[slot] = topw[p];
}

// ---------------- fused up-projection: shared + routed ----------------
// Job space: [0,256): shared 64x128 tiles (32m x 8n), K=1024.
//            [256, 256+4*nseg): routed: seg (e,m0) x 4 n-tiles, K=1024.

__global__ __launch_bounds__(256) void up_all(
    const bf16* __restrict__ xb, const bf16* __restrict__ wsinT,
    const bf16* __restrict__ vsinT, const bf16* __restrict__ ewinT,
    const bf16* __restrict__ evinT, const int* __restrict__ tok_list,
    const float* __restrict__ w_list, const int* __restrict__ counts,
    const int* __restrict__ offs, const int* __restrict__ seg_up,
    const int* __restrict__ nseg_up, bf16* __restrict__ hsb,
    bf16* __restrict__ hre) {
  int j = blockIdx.x;
  int nj = 256 + 4 * nseg_up[0];
  if (j >= nj) return;
  int tid = threadIdx.x, lane = tid & 63, wid = tid >> 6;
  int wr = wid >> 1, wc = wid & 1;

  bool is_shared = (j < 256);
  int m0, n0, cnt = TOK, off_e = 0;
  const bf16 *B1, *B2;
  if (is_shared) {
    m0 = (j >> 3) * 64; n0 = (j & 7) * 128;
    B1 = wsinT + (size_t)n0 * DIM;
    B2 = vsinT + (size_t)n0 * DIM;
  } else {
    int r = j - 256, seg = r >> 2;
    n0 = (r & 3) * 128;
    int sv = seg_up[seg];
    int e = sv >> 16; m0 = sv & 0xffff;
    cnt = counts[e]; off_e = offs[e];
    B1 = ewinT + (size_t)e * HID * DIM + (size_t)n0 * DIM;
    B2 = evinT + (size_t)e * HID * DIM + (size_t)n0 * DIM;
  }

  int arows[2], brows[4];
#pragma unroll
  for (int i = 0; i < 2; ++i) {
    int row = (i * 256 + tid) >> 3;  // 0..63
    arows[i] = is_shared ? (m0 + row) : tok_list[off_e + min(m0 + row, cnt - 1)];
  }
#pragma unroll
  for (int i = 0; i < 4; ++i) brows[i] = (i * 256 + tid) >> 3;  // 0..127

  __shared__ alignas(16) bf16 As[64 * 64], B1s[128 * 64], B2s[128 * 64];
  f32x4 acc1[2][4], acc2[2][4];
  f32x4 z4 = {0.f, 0.f, 0.f, 0.f};
#pragma unroll
  for (int mi = 0; mi < 2; ++mi)
#pragma unroll
    for (int ni = 0; ni < 4; ++ni) { acc1[mi][ni] = z4; acc2[mi][ni] = z4; }

  for (int k0 = 0; k0 < DIM; k0 += 64) {
    __syncthreads();
    stage_rows<2>(xb, DIM, arows, k0, As, tid);
    stage_rows<4>(B1, DIM, brows, k0, B1s, tid);
    stage_rows<4>(B2, DIM, brows, k0, B2s, tid);
    __syncthreads();
#pragma unroll
    for (int ks = 0; ks < 2; ++ks) {
      int r16 = lane & 15, kc = (ks << 2) + (lane >> 4);
      s16x8 a0 = frag(As, wr * 32 + r16, kc);
      s16x8 a1 = frag(As, wr * 32 + 16 + r16, kc);
#pragma unroll
      for (int ni = 0; ni < 4; ++ni) {
        s16x8 b1 = frag(B1s, wc * 64 + ni * 16 + r16, kc);
        s16x8 b2 = frag(B2s, wc * 64 + ni * 16 + r16, kc);
        acc1[0][ni] = MFMA(a0, b1, acc1[0][ni]);
        acc1[1][ni] = MFMA(a1, b1, acc1[1][ni]);
        acc2[0][ni] = MFMA(a0, b2, acc2[0][ni]);
        acc2[1][ni] = MFMA(a1, b2, acc2[1][ni]);
      }
    }
  }
#pragma unroll
  for (int mi = 0; mi < 2; ++mi)
#pragma unroll
    for (int ni = 0; ni < 4; ++ni)
#pragma unroll
      for (int i = 0; i < 4; ++i) {
        int r = wr * 32 + mi * 16 + (lane >> 4) * 4 + i;
        int c = n0 + wc * 64 + ni * 16 + (lane & 15);
        float z = acc1[mi][ni][i], v = acc2[mi][ni][i];
        float h = z / (1.f + __expf(-z)) * v;
        if (is_shared) {
          hsb[(size_t)(m0 + r) * NHS + c] = __float2bfloat16(h);
        } else {
          int gr = m0 + r;
          if (gr < cnt)
            hre[(size_t)(off_e + gr) * HID + c] =
                __float2bfloat16(h * w_list[off_e + gr]);
        }
      }
}

// ---------------- fused down-projection: shared + routed (all-atomic) --------
// out zeroed by memset; every job atomicAdds its 128x128 fp32 tile.
// Job space: [0,128): shared 128x128 (16m x 8n), K=1024.
//            [128, 128+8*nseg): routed seg x 8 n-tiles, K=512.

__global__ __launch_bounds__(256) void down_all(
    const bf16* __restrict__ hsb, const bf16* __restrict__ wsoutT,
    const bf16* __restrict__ hre, const bf16* __restrict__ ewoutT,
    const int* __restrict__ tok_list, const int* __restrict__ counts,
    const int* __restrict__ offs, const int* __restrict__ seg_dn,
    const int* __restrict__ nseg_dn, float* __restrict__ out) {
  int j = blockIdx.x;
  int nj = 128 + 8 * nseg_dn[0];
  if (j >= nj) return;
  int tid = threadIdx.x, lane = tid & 63, wid = tid >> 6;
  int wr = wid >> 1, wc = wid & 1;

  bool is_shared = (j < 128);
  int m0, n0, cnt = TOK, off_e = 0, K, ld;
  const bf16 *A, *B;
  if (is_shared) {
    m0 = (j >> 3) * 128; n0 = (j & 7) * 128;
    A = hsb; ld = NHS; K = NHS;
    B = wsoutT + (size_t)n0 * NHS;
  } else {
    int r = j - 128, seg = r >> 3;
    n0 = (r & 7) * 128;
    int sv = seg_dn[seg];
    int e = sv >> 16; m0 = sv & 0xffff;
    cnt = counts[e]; off_e = offs[e];
    A = hre + (size_t)off_e * HID; ld = HID; K = HID;
    B = ewoutT + (size_t)e * DIM * HID + (size_t)n0 * HID;
  }

  int arows[4], brows[4];
#pragma unroll
  for (int i = 0; i < 4; ++i) {
    int row = (i * 256 + tid) >> 3;  // 0..127
    arows[i] = is_shared ? (m0 + row) : min(m0 + row, cnt - 1);
    brows[i] = row;
  }

  __shared__ alignas(16) bf16 As[128 * 64], Bs[128 * 64];
  f32x4 acc[4][4];
  f32x4 z4 = {0.f, 0.f, 0.f, 0.f};
#pragma unroll
  for (int mi = 0; mi < 4; ++mi)
#pragma unroll
    for (int ni = 0; ni < 4; ++ni) acc[mi][ni] = z4;

  for (int k0 = 0; k0 < K; k0 += 64) {
    __syncthreads();
    stage_rows<4>(A, ld, arows, k0, As, tid);
    stage_rows<4>(B, ld, brows, k0, Bs, tid);
    __syncthreads();
#pragma unroll
    for (int ks = 0; ks < 2; ++ks) {
      int r16 = lane & 15, kc = (ks << 2) + (lane >> 4);
      s16x8 a[4];
#pragma unroll
      for (int mi = 0; mi < 4; ++mi) a[mi] = frag(As, wr * 64 + mi * 16 + r16, kc);
#pragma unroll
      for (int ni = 0; ni < 4; ++ni) {
        s16x8 b = frag(Bs, wc * 64 + ni * 16 + r16, kc);
#pragma unroll
        for (int mi = 0; mi < 4; ++mi) acc[mi][ni] = MFMA(a[mi], b, acc[mi][ni]);
      }
    }
  }
#pragma unroll
  for (int mi = 0; mi < 4; ++mi)
#pragma unroll
    for (int ni = 0; ni < 4; ++ni)
#pragma unroll
      for (int i = 0; i < 4; ++i) {
        int r = wr * 64 + mi * 16 + (lane >> 4) * 4 + i;
        int c = n0 + wc * 64 + ni * 16 + (lane & 15);
        if (is_shared) {
          atomicAdd(&out[(size_t)(m0 + r) * DIM + c], acc[mi][ni][i]);
        } else {
          int gr = m0 + r;
          if (gr < cnt)
            atomicAdd(&out[(size_t)tok_list[off_e + gr] * DIM + c], acc[mi][ni][i]);
        }
      }
}

// ---------------- launcher ----------------

extern "C" void kernel_launch(void* const* d_in, const int* in_sizes, int n_in,
                              void* d_out, int out_size, void* d_ws, size_t ws_size,
                              hipStream_t stream) {
  const float* x      = (const float*)d_in[0];
  const float* gw     = (const float*)d_in[1];
  const float* ws_in  = (const float*)d_in[2];
  const float* vs_in  = (const float*)d_in[3];
  const float* ws_out = (const float*)d_in[4];
  const float* e_win  = (const float*)d_in[5];
  const float* e_vin  = (const float*)d_in[6];
  const float* e_wout = (const float*)d_in[7];
  float* out = (float*)d_out;

  // Workspace layout, peak ~52.5 MB (validated fits in rounds 2-3).
  char* p = (char*)d_ws;
  bf16* xb     = (bf16*)p;  p += (size_t)TOK * DIM * 2;            // 4 MB
  bf16* wsinT  = (bf16*)p;                                         // 2 MB
  bf16* wsoutT = wsinT;                                            // reused after up_all
  p += (size_t)NHS * DIM * 2;
  bf16* vsinT  = (bf16*)p;  p += (size_t)NHS * DIM * 2;            // 2 MB
  bf16* hsb    = (bf16*)p;  p += (size_t)TOK * NHS * 2;            // 4 MB
  bf16* ewinT  = (bf16*)p;                                         // 16 MB
  bf16* ewoutT = ewinT;                                            // reused after up_all
  p += (size_t)NE * DIM * HID * 2;
  bf16* evinT  = (bf16*)p;  p += (size_t)NE * DIM * HID * 2;       // 16 MB
  bf16* hre    = (bf16*)p;  p += (size_t)(NPAIR + 128) * HID * 2;  // 8.25 MB
  int*   topi     = (int*)p;    p += (size_t)NPAIR * 4;
  float* topw     = (float*)p;  p += (size_t)NPAIR * 4;
  int*   tok_list = (int*)p;    p += (size_t)NPAIR * 4;
  float* w_list   = (float*)p;  p += (size_t)NPAIR * 4;
  int*   counts   = (int*)p;    p += 64;
  int*   offs     = (int*)p;    p += 64;
  int*   cursor   = (int*)p;    p += 64;
  int*   seg_up   = (int*)p;    p += 256 * 4;   // worst case 144 segs
  int*   nseg_up  = (int*)p;    p += 64;
  int*   seg_dn   = (int*)p;    p += 128 * 4;   // worst case 80 segs
  int*   nseg_dn  = (int*)p;    p += 64;

  hipMemsetAsync(counts, 0, NE * sizeof(int), stream);
  gate_cast<<<TOK, 256, 0, stream>>>(x, gw, xb, topi, topw, counts);
  route_small<<<1, 64, 0, stream>>>(counts, offs, seg_up, nseg_up,
                                    seg_dn, nseg_dn, cursor);
  scatter_pairs<<<NPAIR / 256, 256, 0, stream>>>(topi, topw, offs, cursor,
                                                 tok_list, w_list);

  prep1<<<18432, 256, 0, stream>>>(ws_in, vs_in, e_win, e_vin,
                                   wsinT, vsinT, ewinT, evinT);

  up_all<<<1024, 256, 0, stream>>>(xb, wsinT, vsinT, ewinT, evinT, tok_list,
                                   w_list, counts, offs, seg_up, nseg_up, hsb, hre);

  // ws_out/e_wout transposes overwrite wsinT/ewinT (dead after up_all).
  prep2<<<9216, 256, 0, stream>>>(ws_out, e_wout, wsoutT, ewoutT);

  hipMemsetAsync(out, 0, (size_t)TOK * DIM * 4, stream);
  down_all<<<768, 256, 0, stream>>>(hsb, wsoutT, hre, ewoutT, tok_list, counts,
                                    offs, seg_dn, nseg_dn, out);
}

// Round 6
// 187.006 us; speedup vs baseline: 2.6710x; 1.5859x over previous
//
#include <hip/hip_runtime.h>
#include <hip/hip_bf16.h>
#include <math.h>

typedef __attribute__((ext_vector_type(4))) float f32x4;
typedef __attribute__((ext_vector_type(8))) short s16x8;
typedef __hip_bfloat16 bf16;

constexpr int TOK = 2048;   // B*S tokens
constexpr int DIM = 1024;   // hidden D
constexpr int HID = 512;    // expert inter H
constexpr int NE  = 16;     // experts
constexpr int NK  = 4;      // top-k
constexpr int NHS = 1024;   // shared inter HS
constexpr int NPAIR = TOK * NK;  // 8192 token-expert pairs

#define MFMA(a, b, c) __builtin_amdgcn_mfma_f32_16x16x32_bf16(a, b, c, 0, 0, 0)

#define GLOAD_LDS(gp, lp)                                                        \
  __builtin_amdgcn_global_load_lds(                                              \
      (const __attribute__((address_space(1))) unsigned int*)(gp),               \
      (__attribute__((address_space(3))) unsigned int*)(lp), 16, 0, 0)

// Stage a (CH*32)-row x 64-col bf16 tile into LDS. rows[i] gives the global
// row for this thread's i-th 16B chunk. LDS slot s of row r holds k-chunk
// s^(r&7): XOR swizzle applied on the per-lane GLOBAL source address; the LDS
// destination stays linear (global_load_lds requirement). 0 bank conflicts
// measured in round 2.
template <int CH>
static __device__ __forceinline__ void stage_rows(const bf16* __restrict__ src, int ld,
                                                  const int* rows, int k0, bf16* lds,
                                                  int tid) {
  int wid = tid >> 6;
#pragma unroll
  for (int i = 0; i < CH; ++i) {
    int c = i * 256 + tid;      // 16B-chunk index
    int row = c >> 3;
    int slot = c & 7;
    int j = slot ^ (row & 7);
    const bf16* g = src + (size_t)rows[i] * ld + k0 + j * 8;
    bf16* l = lds + (size_t)(i * 256 + wid * 64) * 8;  // wave-uniform base
    GLOAD_LDS(g, l);
  }
}

static __device__ __forceinline__ s16x8 frag(const bf16* lds, int row, int kc) {
  return *(const s16x8*)(lds + row * 64 + ((kc ^ (row & 7)) << 3));
}

struct bf16x4 { bf16 a, b, c, d; };

// ---------------- fused transpose+cast prep kernels ----------------
// src [R][C] fp32 -> dst [C][R] bf16, 32x32 tiles, 256 threads flat.

static __device__ __forceinline__ void tr_tile(const float* __restrict__ src,
                                               bf16* __restrict__ dst, int R, int C,
                                               int bx, int by, float t[32][33], int tid) {
  int tx = tid & 31, ty = tid >> 5;  // 32 x 8
  int c0 = bx * 32, r0 = by * 32;
#pragma unroll
  for (int i = 0; i < 32; i += 8) t[ty + i][tx] = src[(size_t)(r0 + ty + i) * C + c0 + tx];
  __syncthreads();
#pragma unroll
  for (int i = 0; i < 32; i += 8)
    dst[(size_t)(c0 + ty + i) * R + r0 + tx] = __float2bfloat16(t[tx][ty + i]);
}

__global__ __launch_bounds__(256) void prep1(const float* __restrict__ ws_in,
                                             const float* __restrict__ vs_in,
                                             const float* __restrict__ e_win,
                                             const float* __restrict__ e_vin,
                                             bf16* __restrict__ wsinT, bf16* __restrict__ vsinT,
                                             bf16* __restrict__ ewinT, bf16* __restrict__ evinT) {
  __shared__ float t[32][33];
  int bid = blockIdx.x, tid = threadIdx.x;
  if (bid < 1024) {
    tr_tile(ws_in, wsinT, DIM, NHS, bid & 31, bid >> 5, t, tid);
  } else if (bid < 2048) {
    int b = bid - 1024;
    tr_tile(vs_in, vsinT, DIM, NHS, b & 31, b >> 5, t, tid);
  } else if (bid < 10240) {
    int b = bid - 2048, e = b >> 9; b &= 511;
    tr_tile(e_win + (size_t)e * DIM * HID, ewinT + (size_t)e * DIM * HID,
            DIM, HID, b & 15, b >> 4, t, tid);
  } else {
    int b = bid - 10240, e = b >> 9; b &= 511;
    tr_tile(e_vin + (size_t)e * DIM * HID, evinT + (size_t)e * DIM * HID,
            DIM, HID, b & 15, b >> 4, t, tid);
  }
}

__global__ __launch_bounds__(256) void prep2(const float* __restrict__ ws_out,
                                             const float* __restrict__ e_wout,
                                             bf16* __restrict__ wsoutT,
                                             bf16* __restrict__ ewoutT) {
  __shared__ float t[32][33];
  int bid = blockIdx.x, tid = threadIdx.x;
  if (bid < 1024) {
    tr_tile(ws_out, wsoutT, NHS, DIM, bid & 31, bid >> 5, t, tid);
  } else {
    int b = bid - 1024, e = b >> 9; b &= 511;
    tr_tile(e_wout + (size_t)e * HID * DIM, ewoutT + (size_t)e * HID * DIM,
            HID, DIM, b & 31, b >> 5, t, tid);
  }
}

// ---------------- gate scores (fp32 exact) + x cast ----------------
// One WAVE per token; lane l owns x[16l..16l+15] (4 x float4 = full 1024-elem
// row across 64 lanes). 16 experts x 4 independent float4 w-loads + dot4;
// butterfly reduce. No dependent-load chains, no serial tail.

__global__ __launch_bounds__(256) void gate_scores(const float* __restrict__ x,
                                                   const float* __restrict__ gw,
                                                   bf16* __restrict__ xb,
                                                   float* __restrict__ scores) {
  int lane = threadIdx.x & 63, wid = threadIdx.x >> 6;
  int t = blockIdx.x * 4 + wid;
  const float* xr = x + (size_t)t * DIM + lane * 16;
  float4 x4[4];
#pragma unroll
  for (int q = 0; q < 4; ++q) x4[q] = *(const float4*)(xr + q * 4);
  {  // cast this token's full row to bf16
    bf16* xo = xb + (size_t)t * DIM + lane * 16;
#pragma unroll
    for (int q = 0; q < 4; ++q) {
      bf16x4 o{__float2bfloat16(x4[q].x), __float2bfloat16(x4[q].y),
               __float2bfloat16(x4[q].z), __float2bfloat16(x4[q].w)};
      *reinterpret_cast<bf16x4*>(xo + q * 4) = o;
    }
  }
  float s[NE];
#pragma unroll
  for (int e = 0; e < NE; ++e) {
    const float* wr_ = gw + (size_t)e * DIM + lane * 16;
    float a = 0.f;
#pragma unroll
    for (int q = 0; q < 4; ++q) {
      float4 w4 = *(const float4*)(wr_ + q * 4);
      a += x4[q].x * w4.x + x4[q].y * w4.y + x4[q].z * w4.z + x4[q].w * w4.w;
    }
    s[e] = a;
  }
#pragma unroll
  for (int e = 0; e < NE; ++e)
#pragma unroll
    for (int off = 32; off; off >>= 1) s[e] += __shfl_xor(s[e], off);
  if (lane == 0) {
#pragma unroll
    for (int e = 0; e < NE; ++e) scores[(size_t)t * NE + e] = s[e];
  }
}

// One THREAD per token: sigmoid + top-4 + LDS histogram -> 16 atomics/block.
__global__ __launch_bounds__(256) void topk_hist(const float* __restrict__ scores,
                                                 int* __restrict__ topi,
                                                 float* __restrict__ topw,
                                                 int* __restrict__ counts) {
  __shared__ int h[NE];
  int tid = threadIdx.x;
  int t = blockIdx.x * 256 + tid;
  if (tid < NE) h[tid] = 0;
  __syncthreads();
  float g[NE];
  const float* sr = scores + (size_t)t * NE;
#pragma unroll
  for (int q = 0; q < 4; ++q) {
    float4 v = *(const float4*)(sr + q * 4);
    g[q * 4 + 0] = 1.f / (1.f + expf(-v.x));
    g[q * 4 + 1] = 1.f / (1.f + expf(-v.y));
    g[q * 4 + 2] = 1.f / (1.f + expf(-v.z));
    g[q * 4 + 3] = 1.f / (1.f + expf(-v.w));
  }
  unsigned used = 0;
  int bi[NK]; float bv[NK];
  float sum = 0.f;
#pragma unroll
  for (int j = 0; j < NK; ++j) {        // lax.top_k tie-break: lowest index first
    int best = 0; float v = -1e30f;
#pragma unroll
    for (int e = 0; e < NE; ++e)
      if (!((used >> e) & 1u) && g[e] > v) { v = g[e]; best = e; }
    used |= 1u << best; bi[j] = best; bv[j] = v; sum += v;
  }
  float inv = 1.f / sum;
#pragma unroll
  for (int j = 0; j < NK; ++j) {
    topi[t * NK + j] = bi[j];
    topw[t * NK + j] = bv[j] * inv;
    atomicAdd(&h[bi[j]], 1);
  }
  __syncthreads();
  if (tid < NE) atomicAdd(&counts[tid], h[tid]);
}

// Tiny serial kernel: offsets, segment lists, cursor reset. ~500 scalar ops.
__global__ __launch_bounds__(64) void route_small(const int* __restrict__ counts,
                                                  int* __restrict__ offs,
                                                  int* __restrict__ seg_up,
                                                  int* __restrict__ nseg_up,
                                                  int* __restrict__ seg_dn,
                                                  int* __restrict__ nseg_dn,
                                                  int* __restrict__ cursor) {
  if (threadIdx.x != 0) return;
  int o = 0;
#pragma unroll
  for (int e = 0; e < NE; ++e) { offs[e] = o; cursor[e * 32] = 0; o += counts[e]; }
  int s = 0;
  for (int e = 0; e < NE; ++e)
    for (int m = 0; m < counts[e]; m += 64) seg_up[s++] = (e << 16) | m;
  nseg_up[0] = s;
  s = 0;
  for (int e = 0; e < NE; ++e)
    for (int m = 0; m < counts[e]; m += 128) seg_dn[s++] = (e << 16) | m;
  nseg_dn[0] = s;
}

// Parallel compaction: each pair takes a slot via per-expert atomic cursor
// (padded to one cacheline per expert). Slot order within an expert is
// non-deterministic but output-invariant.
__global__ __launch_bounds__(256) void scatter_pairs(const int* __restrict__ topi,
                                                     const float* __restrict__ topw,
                                                     const int* __restrict__ offs,
                                                     int* __restrict__ cursor,
                                                     int* __restrict__ tok_list,
                                                     float* __restrict__ w_list) {
  int p = blockIdx.x * 256 + threadIdx.x;
  if (p >= NPAIR) return;
  int e = topi[p];
  int rank = atomicAdd(&cursor[e * 32], 1);
  int slot = offs[e] + rank;
  tok_list[slot] = p >> 2;   // token id
  w_list[slot] = topw[p];
}

// ---------------- fused up-projection: shared + routed ----------------
// Job space: [0,256): shared 64x128 tiles (32m x 8n), K=1024.
//            [256, 256+4*nseg): routed: seg (e,m0) x 4 n-tiles, K=1024.

__global__ __launch_bounds__(256) void up_all(
    const bf16* __restrict__ xb, const bf16* __restrict__ wsinT,
    const bf16* __restrict__ vsinT, const bf16* __restrict__ ewinT,
    const bf16* __restrict__ evinT, const int* __restrict__ tok_list,
    const float* __restrict__ w_list, const int* __restrict__ counts,
    const int* __restrict__ offs, const int* __restrict__ seg_up,
    const int* __restrict__ nseg_up, bf16* __restrict__ hsb,
    bf16* __restrict__ hre) {
  int j = blockIdx.x;
  int nj = 256 + 4 * nseg_up[0];
  if (j >= nj) return;
  int tid = threadIdx.x, lane = tid & 63, wid = tid >> 6;
  int wr = wid >> 1, wc = wid & 1;

  bool is_shared = (j < 256);
  int m0, n0, cnt = TOK, off_e = 0;
  const bf16 *B1, *B2;
  if (is_shared) {
    m0 = (j >> 3) * 64; n0 = (j & 7) * 128;
    B1 = wsinT + (size_t)n0 * DIM;
    B2 = vsinT + (size_t)n0 * DIM;
  } else {
    int r = j - 256, seg = r >> 2;
    n0 = (r & 3) * 128;
    int sv = seg_up[seg];
    int e = sv >> 16; m0 = sv & 0xffff;
    cnt = counts[e]; off_e = offs[e];
    B1 = ewinT + (size_t)e * HID * DIM + (size_t)n0 * DIM;
    B2 = evinT + (size_t)e * HID * DIM + (size_t)n0 * DIM;
  }

  int arows[2], brows[4];
#pragma unroll
  for (int i = 0; i < 2; ++i) {
    int row = (i * 256 + tid) >> 3;  // 0..63
    arows[i] = is_shared ? (m0 + row) : tok_list[off_e + min(m0 + row, cnt - 1)];
  }
#pragma unroll
  for (int i = 0; i < 4; ++i) brows[i] = (i * 256 + tid) >> 3;  // 0..127

  __shared__ alignas(16) bf16 As[64 * 64], B1s[128 * 64], B2s[128 * 64];
  f32x4 acc1[2][4], acc2[2][4];
  f32x4 z4 = {0.f, 0.f, 0.f, 0.f};
#pragma unroll
  for (int mi = 0; mi < 2; ++mi)
#pragma unroll
    for (int ni = 0; ni < 4; ++ni) { acc1[mi][ni] = z4; acc2[mi][ni] = z4; }

  for (int k0 = 0; k0 < DIM; k0 += 64) {
    __syncthreads();
    stage_rows<2>(xb, DIM, arows, k0, As, tid);
    stage_rows<4>(B1, DIM, brows, k0, B1s, tid);
    stage_rows<4>(B2, DIM, brows, k0, B2s, tid);
    __syncthreads();
#pragma unroll
    for (int ks = 0; ks < 2; ++ks) {
      int r16 = lane & 15, kc = (ks << 2) + (lane >> 4);
      s16x8 a0 = frag(As, wr * 32 + r16, kc);
      s16x8 a1 = frag(As, wr * 32 + 16 + r16, kc);
#pragma unroll
      for (int ni = 0; ni < 4; ++ni) {
        s16x8 b1 = frag(B1s, wc * 64 + ni * 16 + r16, kc);
        s16x8 b2 = frag(B2s, wc * 64 + ni * 16 + r16, kc);
        acc1[0][ni] = MFMA(a0, b1, acc1[0][ni]);
        acc1[1][ni] = MFMA(a1, b1, acc1[1][ni]);
        acc2[0][ni] = MFMA(a0, b2, acc2[0][ni]);
        acc2[1][ni] = MFMA(a1, b2, acc2[1][ni]);
      }
    }
  }
#pragma unroll
  for (int mi = 0; mi < 2; ++mi)
#pragma unroll
    for (int ni = 0; ni < 4; ++ni)
#pragma unroll
      for (int i = 0; i < 4; ++i) {
        int r = wr * 32 + mi * 16 + (lane >> 4) * 4 + i;
        int c = n0 + wc * 64 + ni * 16 + (lane & 15);
        float z = acc1[mi][ni][i], v = acc2[mi][ni][i];
        float h = z / (1.f + __expf(-z)) * v;
        if (is_shared) {
          hsb[(size_t)(m0 + r) * NHS + c] = __float2bfloat16(h);
        } else {
          int gr = m0 + r;
          if (gr < cnt)
            hre[(size_t)(off_e + gr) * HID + c] =
                __float2bfloat16(h * w_list[off_e + gr]);
        }
      }
}

// ---------------- fused down-projection: shared + routed (all-atomic) --------
// out zeroed by memset; every job atomicAdds its 128x128 fp32 tile.
// Job space: [0,128): shared 128x128 (16m x 8n), K=1024.
//            [128, 128+8*nseg): routed seg x 8 n-tiles, K=512.

__global__ __launch_bounds__(256) void down_all(
    const bf16* __restrict__ hsb, const bf16* __restrict__ wsoutT,
    const bf16* __restrict__ hre, const bf16* __restrict__ ewoutT,
    const int* __restrict__ tok_list, const int* __restrict__ counts,
    const int* __restrict__ offs, const int* __restrict__ seg_dn,
    const int* __restrict__ nseg_dn, float* __restrict__ out) {
  int j = blockIdx.x;
  int nj = 128 + 8 * nseg_dn[0];
  if (j >= nj) return;
  int tid = threadIdx.x, lane = tid & 63, wid = tid >> 6;
  int wr = wid >> 1, wc = wid & 1;

  bool is_shared = (j < 128);
  int m0, n0, cnt = TOK, off_e = 0, K, ld;
  const bf16 *A, *B;
  if (is_shared) {
    m0 = (j >> 3) * 128; n0 = (j & 7) * 128;
    A = hsb; ld = NHS; K = NHS;
    B = wsoutT + (size_t)n0 * NHS;
  } else {
    int r = j - 128, seg = r >> 3;
    n0 = (r & 7) * 128;
    int sv = seg_dn[seg];
    int e = sv >> 16; m0 = sv & 0xffff;
    cnt = counts[e]; off_e = offs[e];
    A = hre + (size_t)off_e * HID; ld = HID; K = HID;
    B = ewoutT + (size_t)e * DIM * HID + (size_t)n0 * HID;
  }

  int arows[4], brows[4];
#pragma unroll
  for (int i = 0; i < 4; ++i) {
    int row = (i * 256 + tid) >> 3;  // 0..127
    arows[i] = is_shared ? (m0 + row) : min(m0 + row, cnt - 1);
    brows[i] = row;
  }

  __shared__ alignas(16) bf16 As[128 * 64], Bs[128 * 64];
  f32x4 acc[4][4];
  f32x4 z4 = {0.f, 0.f, 0.f, 0.f};
#pragma unroll
  for (int mi = 0; mi < 4; ++mi)
#pragma unroll
    for (int ni = 0; ni < 4; ++ni) acc[mi][ni] = z4;

  for (int k0 = 0; k0 < K; k0 += 64) {
    __syncthreads();
    stage_rows<4>(A, ld, arows, k0, As, tid);
    stage_rows<4>(B, ld, brows, k0, Bs, tid);
    __syncthreads();
#pragma unroll
    for (int ks = 0; ks < 2; ++ks) {
      int r16 = lane & 15, kc = (ks << 2) + (lane >> 4);
      s16x8 a[4];
#pragma unroll
      for (int mi = 0; mi < 4; ++mi) a[mi] = frag(As, wr * 64 + mi * 16 + r16, kc);
#pragma unroll
      for (int ni = 0; ni < 4; ++ni) {
        s16x8 b = frag(Bs, wc * 64 + ni * 16 + r16, kc);
#pragma unroll
        for (int mi = 0; mi < 4; ++mi) acc[mi][ni] = MFMA(a[mi], b, acc[mi][ni]);
      }
    }
  }
#pragma unroll
  for (int mi = 0; mi < 4; ++mi)
#pragma unroll
    for (int ni = 0; ni < 4; ++ni)
#pragma unroll
      for (int i = 0; i < 4; ++i) {
        int r = wr * 64 + mi * 16 + (lane >> 4) * 4 + i;
        int c = n0 + wc * 64 + ni * 16 + (lane & 15);
        if (is_shared) {
          atomicAdd(&out[(size_t)(m0 + r) * DIM + c], acc[mi][ni][i]);
        } else {
          int gr = m0 + r;
          if (gr < cnt)
            atomicAdd(&out[(size_t)tok_list[off_e + gr] * DIM + c], acc[mi][ni][i]);
        }
      }
}

// ---------------- launcher ----------------

extern "C" void kernel_launch(void* const* d_in, const int* in_sizes, int n_in,
                              void* d_out, int out_size, void* d_ws, size_t ws_size,
                              hipStream_t stream) {
  const float* x      = (const float*)d_in[0];
  const float* gw     = (const float*)d_in[1];
  const float* ws_in  = (const float*)d_in[2];
  const float* vs_in  = (const float*)d_in[3];
  const float* ws_out = (const float*)d_in[4];
  const float* e_win  = (const float*)d_in[5];
  const float* e_vin  = (const float*)d_in[6];
  const float* e_wout = (const float*)d_in[7];
  float* out = (float*)d_out;

  // Workspace layout, peak ~52.7 MB (validated fits in rounds 2-4).
  char* p = (char*)d_ws;
  bf16* xb     = (bf16*)p;  p += (size_t)TOK * DIM * 2;            // 4 MB
  bf16* wsinT  = (bf16*)p;                                         // 2 MB
  bf16* wsoutT = wsinT;                                            // reused after up_all
  p += (size_t)NHS * DIM * 2;
  bf16* vsinT  = (bf16*)p;  p += (size_t)NHS * DIM * 2;            // 2 MB
  bf16* hsb    = (bf16*)p;  p += (size_t)TOK * NHS * 2;            // 4 MB
  bf16* ewinT  = (bf16*)p;                                         // 16 MB
  bf16* ewoutT = ewinT;                                            // reused after up_all
  p += (size_t)NE * DIM * HID * 2;
  bf16* evinT  = (bf16*)p;  p += (size_t)NE * DIM * HID * 2;       // 16 MB
  bf16* hre    = (bf16*)p;  p += (size_t)(NPAIR + 128) * HID * 2;  // 8.25 MB
  int*   topi     = (int*)p;    p += (size_t)NPAIR * 4;
  float* topw     = (float*)p;  p += (size_t)NPAIR * 4;
  int*   tok_list = (int*)p;    p += (size_t)NPAIR * 4;
  float* w_list   = (float*)p;  p += (size_t)NPAIR * 4;
  float* scores   = (float*)p;  p += (size_t)TOK * NE * 4;         // 128 KB
  int*   counts   = (int*)p;    p += 64;
  int*   offs     = (int*)p;    p += 64;
  int*   cursor   = (int*)p;    p += NE * 32 * 4;                  // 1 line/expert
  int*   seg_up   = (int*)p;    p += 256 * 4;   // worst case 144 segs
  int*   nseg_up  = (int*)p;    p += 64;
  int*   seg_dn   = (int*)p;    p += 128 * 4;   // worst case 80 segs
  int*   nseg_dn  = (int*)p;    p += 64;

  hipMemsetAsync(counts, 0, NE * sizeof(int), stream);
  gate_scores<<<TOK / 4, 256, 0, stream>>>(x, gw, xb, scores);
  topk_hist<<<TOK / 256, 256, 0, stream>>>(scores, topi, topw, counts);
  route_small<<<1, 64, 0, stream>>>(counts, offs, seg_up, nseg_up,
                                    seg_dn, nseg_dn, cursor);
  scatter_pairs<<<NPAIR / 256, 256, 0, stream>>>(topi, topw, offs, cursor,
                                                 tok_list, w_list);

  prep1<<<18432, 256, 0, stream>>>(ws_in, vs_in, e_win, e_vin,
                                   wsinT, vsinT, ewinT, evinT);

  up_all<<<1024, 256, 0, stream>>>(xb, wsinT, vsinT, ewinT, evinT, tok_list,
                                   w_list, counts, offs, seg_up, nseg_up, hsb, hre);

  // ws_out/e_wout transposes overwrite wsinT/ewinT (dead after up_all).
  prep2<<<9216, 256, 0, stream>>>(ws_out, e_wout, wsoutT, ewoutT);

  hipMemsetAsync(out, 0, (size_t)TOK * DIM * 4, stream);
  down_all<<<768, 256, 0, stream>>>(hsb, wsoutT, hre, ewoutT, tok_list, counts,
                                    offs, seg_dn, nseg_dn, out);
}